// Round 8
// baseline (1197.578 us; speedup 1.0000x reference)
//
#include <hip/hip_runtime.h>
#include <hip/hip_bf16.h>
#include <cstdint>
#include <cstddef>

typedef __bf16 bf16;
typedef __bf16 bf16x8 __attribute__((ext_vector_type(8)));
typedef float f32x4 __attribute__((ext_vector_type(4)));

#define BATCH 8192
#define IN_DIM 2048
#define HID 2048
#define RANK 512
#define KDIM 4096    // IN+HID
#define NG 2048      // 4*RANK

// ---------------- helpers ----------------

__device__ __forceinline__ void gload16(const void* g, void* l) {
  __builtin_amdgcn_global_load_lds(
      (const __attribute__((address_space(1))) unsigned int*)g,
      (__attribute__((address_space(3))) unsigned int*)l, 16, 0, 0);
}

__device__ __forceinline__ float sigmoidf_(float x) {
  return 1.0f / (1.0f + __expf(-x));
}
__device__ __forceinline__ float tanhf_(float x) {
  return 1.0f - 2.0f / (__expf(2.0f * x) + 1.0f);
}

#define GBAR  __builtin_amdgcn_s_barrier()
#define LGKM0 asm volatile("s_waitcnt lgkmcnt(0)" ::: "memory")
#define VMC2  asm volatile("s_waitcnt vmcnt(2)" ::: "memory")
#define VMC4  asm volatile("s_waitcnt vmcnt(4)" ::: "memory")
#define VMC8  asm volatile("s_waitcnt vmcnt(8)" ::: "memory")
#define SB0   __builtin_amdgcn_sched_barrier(0)

// =================== 512-thread core (k_gemm1) — round-5 proven ===================

__device__ __forceinline__ void stage_half(const bf16* __restrict__ g0, int ld,
                                           int row0, int kcol, bf16* lbase, int tid) {
  const int wid = tid >> 6;
  #pragma unroll
  for (int q = 0; q < 2; ++q) {
    const int slot = q * 512 + tid;
    const int row = slot >> 3, cb = slot & 7;
    const int gcb = cb ^ (row & 7);
    gload16(g0 + (size_t)(row0 + row) * ld + kcol + gcb * 8,
            lbase + (size_t)(q * 64 + wid * 8) * 64);
  }
}

#define LD_Ap(PA, Q)                                                          \
  _Pragma("unroll") for (int ai = 0; ai < 2; ++ai)                            \
  _Pragma("unroll") for (int ks = 0; ks < 2; ++ks)                            \
    a[ai][ks] = *(const bf16x8*)((PA) + (wm + (Q) * 32 + ai * 16 + lr) * 64   \
                                 + ((((ks << 2) | lk) ^ sw) << 3));

#define LD_Bp(PB)                                                             \
  _Pragma("unroll") for (int j = 0; j < 4; ++j)                               \
  _Pragma("unroll") for (int ks = 0; ks < 2; ++ks)                            \
    b[j][ks] = *(const bf16x8*)((PB) + (wn + j * 16 + lr) * 64                \
                                 + ((((ks << 2) | lk) ^ sw) << 3));

#define MFMAQ(Q)                                                              \
  _Pragma("unroll") for (int ai = 0; ai < 2; ++ai)                            \
  _Pragma("unroll") for (int ks = 0; ks < 2; ++ks)                            \
  _Pragma("unroll") for (int j = 0; j < 4; ++j)                               \
    acc[(Q) * 2 + ai][j] = __builtin_amdgcn_mfma_f32_16x16x32_bf16(           \
        a[ai][ks], b[j][ks], acc[(Q) * 2 + ai][j], 0, 0, 0);

#define PHASE3(TOP, STAGE, Q, PFOP, TAILVM) \
  {                                         \
    TOP;                                    \
    STAGE;                                  \
    GBAR;                                   \
    LGKM0;                                  \
    __builtin_amdgcn_s_setprio(1);          \
    MFMAQ(Q);                               \
    __builtin_amdgcn_s_setprio(0);          \
    PFOP;                                   \
    SB0;                                    \
    TAILVM;                                 \
    GBAR;                                   \
  }

// 256x256 tile, BK=64, 8 waves. A dbuf (2x32KB), B 3-ring (3x32KB).
template <int NT>
__device__ __forceinline__ void gemm_core(const bf16* __restrict__ A, int lda, int m0,
                                          const bf16* __restrict__ B, int ldb, int n0,
                                          bf16* lds, f32x4 (&acc)[8][4]) {
  const int tid = threadIdx.x;
  const int wid = tid >> 6, lane = tid & 63;
  const int wm = (wid >> 2) * 128, wn = (wid & 3) * 64;
  const int lr = lane & 15, lk = lane >> 4;
  const int sw = lr & 7;
  bf16x8 a[2][2], b[4][2];

  bf16* Ab0 = lds;
  bf16* Ab1 = lds + 16384;
  bf16* Rg0 = lds + 2 * 16384;
  bf16* Rg1 = lds + 3 * 16384;
  bf16* Rg2 = lds + 4 * 16384;

  #pragma unroll
  for (int i = 0; i < 8; ++i)
    #pragma unroll
    for (int j = 0; j < 4; ++j) acc[i][j] = (f32x4){0.f, 0.f, 0.f, 0.f};

  stage_half(A, lda, m0,       0,   Ab0,        tid);
  stage_half(A, lda, m0 + 128, 0,   Ab0 + 8192, tid);
  stage_half(B, ldb, n0,       0,   Rg0,        tid);
  stage_half(B, ldb, n0 + 128, 0,   Rg0 + 8192, tid);
  stage_half(B, ldb, n0,       64,  Rg1,        tid);
  stage_half(B, ldb, n0 + 128, 64,  Rg1 + 8192, tid);
  stage_half(B, ldb, n0,       128, Rg2,        tid);
  stage_half(B, ldb, n0 + 128, 128, Rg2 + 8192, tid);
  VMC8;
  GBAR;
  LD_Bp(Rg0);

  bf16 *pBc = Rg0, *pBn = Rg1, *pBn2 = Rg2;
  bf16 *pAc = Ab0, *pAa = Ab1;
  for (int c = 0; c < NT; ++c) {
    const int kc1 = ((c + 1) & (NT - 1)) * 64;
    const int kc3 = ((c + 3) & (NT - 1)) * 64;
    PHASE3(LD_Ap(pAc, 0), stage_half(A, lda, m0,       kc1, pAa,        tid), 0,
           LD_Ap(pAc, 1), (void)0);
    PHASE3((void)0,       stage_half(A, lda, m0 + 128, kc1, pAa + 8192, tid), 1,
           LD_Ap(pAc, 2), (void)0);
    PHASE3((void)0,       stage_half(B, ldb, n0,       kc3, pBc,        tid), 2,
           LD_Ap(pAc, 3), (void)0);
    PHASE3((void)0,       stage_half(B, ldb, n0 + 128, kc3, pBc + 8192, tid), 3,
           LD_Bp(pBn),    VMC4);
    bf16* tt = pBc; pBc = pBn; pBn = pBn2; pBn2 = tt;
    tt = pAc; pAc = pAa; pAa = tt;
  }
}

// =================== 1024-thread fused kernel: 4 gates concurrent ===================
// 16 waves (4M x 4N), each owns a 64x64 tile of ALL FOUR gates.
// Steps c = 0..31: gate G = c&3, K-tile kk = c>>2. acc[4][4][4] (256 regs)
// is the only carried state — MFMA accumulators, not spillable VALU state.

__device__ __forceinline__ void stage_halfF(const bf16* __restrict__ g0, int ld,
                                            int row0, int kcol, bf16* lbase, int tid) {
  const int wid = tid >> 6;
  const int row = tid >> 3, cb = tid & 7;
  const int gcb = cb ^ (row & 7);
  gload16(g0 + (size_t)(row0 + row) * ld + kcol + gcb * 8,
          lbase + (size_t)wid * 512);
}

#define LD_ApF(PA, Q)                                                         \
  _Pragma("unroll") for (int ks = 0; ks < 2; ++ks)                            \
    a[(Q) & 1][ks] = *(const bf16x8*)((PA) + (wm + (Q) * 16 + lr) * 64        \
                                 + ((((ks << 2) | lk) ^ sw) << 3));

#define MFMAQ4(G, Q)                                                          \
  _Pragma("unroll") for (int ks = 0; ks < 2; ++ks)                            \
  _Pragma("unroll") for (int j = 0; j < 4; ++j)                               \
    acc[(G)][(Q)][j] = __builtin_amdgcn_mfma_f32_16x16x32_bf16(               \
        a[(Q) & 1][ks], b[j][ks], acc[(G)][(Q)][j], 0, 0, 0);

#define PHASEF4(G, Q, TOP, STAGE, PFOP, TAILVM) \
  {                                             \
    TOP;                                        \
    STAGE;                                      \
    GBAR;                                       \
    LGKM0;                                      \
    __builtin_amdgcn_s_setprio(1);              \
    MFMAQ4(G, Q);                               \
    __builtin_amdgcn_s_setprio(0);              \
    TAILVM;                                     \
    PFOP;                                       \
    SB0;                                        \
    GBAR;                                       \
  }

// B-panel pointer for the step-(c+3) stage, gate (G+3)&3 — literal G folds it.
#define VTG(G) ((G) == 0 ? Vg3 : (G) == 1 ? Vg0 : (G) == 2 ? Vg1 : Vg2)

// One pipeline step (gate G of K-tile t). Ledger (1 load/thread/stage):
// at Q3 pre-wait, outstanding FIFO = B(c+1)x2, B(c+2)x2, A(c+1)x2, B(c+3)x2;
// vmcnt(2) completes everything except B(c+3) => step c+1's reads are safe.
#define STEPF(G)                                                            \
  {                                                                         \
    const int kk1 = ((G) == 3) ? ((t + 1) & 7) : (t & 7);                   \
    const int acol1 = (((G) + 1) & 3) * 512 + kk1 * 64;                     \
    const int kk3 = ((G) >= 1) ? ((t + 1) & 7) : (t & 7);                   \
    const int bcol3 = kk3 * 64;                                             \
    const bf16* vb3 = VTG(G);                                               \
    PHASEF4(G, 0, LD_Bp(pBc); LD_ApF(pAc, 0),                               \
            stage_halfF(Rb, NG, m0, acol1, pAa, tid),                       \
            LD_ApF(pAc, 1), (void)0);                                       \
    PHASEF4(G, 1, (void)0,                                                  \
            stage_halfF(Rb, NG, m0 + 128, acol1, pAa + 8192, tid),          \
            LD_ApF(pAc, 2), (void)0);                                       \
    PHASEF4(G, 2, (void)0,                                                  \
            stage_halfF(vb3, RANK, n0, bcol3, pBc, tid),                    \
            LD_ApF(pAc, 3), (void)0);                                       \
    PHASEF4(G, 3, (void)0,                                                  \
            stage_halfF(vb3, RANK, n0 + 128, bcol3, pBc + 8192, tid),       \
            (void)0, VMC2);                                                 \
    bf16* tt = pBc; pBc = pBn; pBn = pBn2; pBn2 = tt;                       \
    tt = pAc; pAc = pAa; pAa = tt;                                          \
  }

__launch_bounds__(1024, 1)
__global__ void k_fused(const bf16* __restrict__ Rb,   // [8192][2048]
                        const bf16* __restrict__ Vt,   // [4][2048][512]
                        const float* __restrict__ bi, const float* __restrict__ bf_,
                        const float* __restrict__ bc, const float* __restrict__ bo,
                        const float* __restrict__ cin, // [8192][2048] f32
                        float* __restrict__ hout, float* __restrict__ cout) {
  __shared__ __align__(16) bf16 lds[81920];   // 160 KB
  const int bx = blockIdx.x;                  // 256 blocks
  const int id = (bx & 7) * 32 + (bx >> 3);   // XCD-bijective swizzle
  const int m0 = (id >> 3) * 256, n0 = (id & 7) * 256;
  const int tid = threadIdx.x;
  const int wid = tid >> 6, lane = tid & 63;
  const int wm = (wid >> 2) * 64, wn = (wid & 3) * 64;
  const int lr = lane & 15, lk = lane >> 4;
  const int sw = lr & 7;
  bf16x8 a[2][2], b[4][2];

  const bf16* Vg0 = Vt;
  const bf16* Vg1 = Vt + (size_t)1 * HID * RANK;
  const bf16* Vg2 = Vt + (size_t)2 * HID * RANK;
  const bf16* Vg3 = Vt + (size_t)3 * HID * RANK;

  bf16* Ab0 = lds;
  bf16* Ab1 = lds + 16384;
  bf16* Rg0 = lds + 2 * 16384;
  bf16* Rg1 = lds + 3 * 16384;
  bf16* Rg2 = lds + 4 * 16384;

  f32x4 acc[4][4][4];   // [gate][m-frag][n-frag]
  #pragma unroll
  for (int g = 0; g < 4; ++g)
    #pragma unroll
    for (int i = 0; i < 4; ++i)
      #pragma unroll
      for (int j = 0; j < 4; ++j) acc[g][i][j] = (f32x4){0.f, 0.f, 0.f, 0.f};

  // Prologue: A(0) [gate0 kk0], B(0)=Vg0, B(1)=Vg1, B(2)=Vg2 (col 0 each).
  stage_halfF(Rb,  NG,   m0,       0, Ab0,        tid);
  stage_halfF(Rb,  NG,   m0 + 128, 0, Ab0 + 8192, tid);
  stage_halfF(Vg0, RANK, n0,       0, Rg0,        tid);
  stage_halfF(Vg0, RANK, n0 + 128, 0, Rg0 + 8192, tid);
  stage_halfF(Vg1, RANK, n0,       0, Rg1,        tid);
  stage_halfF(Vg1, RANK, n0 + 128, 0, Rg1 + 8192, tid);
  stage_halfF(Vg2, RANK, n0,       0, Rg2,        tid);
  stage_halfF(Vg2, RANK, n0 + 128, 0, Rg2 + 8192, tid);
  VMC4;   // A(0),B(0) drained; B(1),B(2) in flight
  GBAR;

  bf16 *pBc = Rg0, *pBn = Rg1, *pBn2 = Rg2;
  bf16 *pAc = Ab0, *pAa = Ab1;
  #pragma unroll 1
  for (int t = 0; t < 8; ++t) {
    STEPF(0);
    STEPF(1);
    STEPF(2);
    STEPF(3);
  }

  // ---- LSTM combine from the four accumulators ----
  #pragma unroll
  for (int j = 0; j < 4; ++j) {
    const int col = n0 + wn + j * 16 + lr;
    const float bji = bi[col], bjf = bf_[col], bjc = bc[col], bjo = bo[col];
    #pragma unroll
    for (int i = 0; i < 4; ++i)
      #pragma unroll
      for (int v = 0; v < 4; ++v) {
        const int row = m0 + wm + i * 16 + lk * 4 + v;
        const float gv_i = sigmoidf_(acc[0][i][j][v] + bji);
        const float gv_f = sigmoidf_(acc[1][i][j][v] + bjf);
        const float gv_c = tanhf_(acc[2][i][j][v] + bjc);
        const float gv_o = sigmoidf_(acc[3][i][j][v] + bjo);
        const float cn = gv_f * cin[(size_t)row * HID + col] + gv_i * gv_c;
        cout[(size_t)row * HID + col] = cn;
        hout[(size_t)row * HID + col] = gv_o * tanhf_(cn);
      }
  }
}

// ---------------- convert & concat x,h -> bf16 combined [8192][4096] ----------------

__global__ void k_convert_combined(const float* __restrict__ x,
                                   const float* __restrict__ h,
                                   bf16* __restrict__ out) {
  size_t i4 = (size_t)blockIdx.x * blockDim.x + threadIdx.x;
  size_t base = i4 * 4;
  int col = (int)(base & (KDIM - 1));
  size_t row = base >> 12;
  const float* src = (col < IN_DIM) ? (x + row * IN_DIM + col)
                                    : (h + row * (size_t)HID + (col - IN_DIM));
  float4 v = *(const float4*)src;
  union { bf16 b[4]; uint2 u; } p;
  p.b[0] = (bf16)v.x; p.b[1] = (bf16)v.y; p.b[2] = (bf16)v.z; p.b[3] = (bf16)v.w;
  *(uint2*)(out + base) = p.u;
}

// ---------------- tiled transpose + convert, 4 gates per launch ----------------

__global__ void k_tconv4(const float* __restrict__ s0, const float* __restrict__ s1,
                         const float* __restrict__ s2, const float* __restrict__ s3,
                         bf16* __restrict__ out, int nrow, int ncol,
                         long ostride, long gstride) {
  __shared__ float t[32][33];
  const float* in = blockIdx.z == 0 ? s0 : blockIdx.z == 1 ? s1
                  : blockIdx.z == 2 ? s2 : s3;
  bf16* o = out + (size_t)blockIdx.z * gstride;
  int c0 = blockIdx.x * 32, r0 = blockIdx.y * 32;
  int tx = threadIdx.x, ty = threadIdx.y;
  #pragma unroll
  for (int yy = ty; yy < 32; yy += 8)
    t[yy][tx] = in[(size_t)(r0 + yy) * ncol + c0 + tx];
  __syncthreads();
  #pragma unroll
  for (int yy = ty; yy < 32; yy += 8)
    o[(size_t)(c0 + yy) * ostride + r0 + tx] = (bf16)t[tx][yy];
}

// ---------------- GEMM1: combined @ [Ui|Uf|Uc|Uo] -> R bf16 [8192][2048] ----------------

__launch_bounds__(512, 2)
__global__ void k_gemm1(const bf16* __restrict__ A,   // [8192][4096]
                        const bf16* __restrict__ Bt,  // [2048][4096]
                        bf16* __restrict__ R) {       // [8192][2048]
  __shared__ __align__(16) bf16 lds[81920];   // 160 KB
  const int bx = blockIdx.x;                  // 256 blocks
  const int id = (bx & 7) * 32 + (bx >> 3);   // XCD-bijective swizzle
  const int m0 = (id >> 3) * 256, n0 = (id & 7) * 256;
  f32x4 acc[8][4];
  gemm_core<KDIM / 64>(A, KDIM, m0, Bt, KDIM, n0, lds, acc);

  const int tid = threadIdx.x;
  const int wid = tid >> 6, lane = tid & 63;
  const int wm = (wid >> 2) * 128, wn = (wid & 3) * 64;
  const int lr = lane & 15, lk = lane >> 4;
  #pragma unroll
  for (int i = 0; i < 8; ++i)
    #pragma unroll
    for (int j = 0; j < 4; ++j)
      #pragma unroll
      for (int v = 0; v < 4; ++v)
        R[(size_t)(m0 + wm + i * 16 + lk * 4 + v) * NG + (n0 + wn + j * 16 + lr)] =
            (bf16)acc[i][j][v];
}

// ---------------- launch ----------------

extern "C" void kernel_launch(void* const* d_in, const int* in_sizes, int n_in,
                              void* d_out, int out_size, void* d_ws, size_t ws_size,
                              hipStream_t stream) {
  const float* x = (const float*)d_in[0];
  const float* h = (const float*)d_in[1];
  const float* c = (const float*)d_in[2];
  const float* U[4] = {(const float*)d_in[3], (const float*)d_in[6],
                       (const float*)d_in[9], (const float*)d_in[12]};
  const float* V[4] = {(const float*)d_in[4], (const float*)d_in[7],
                       (const float*)d_in[10], (const float*)d_in[13]};
  const float* b[4] = {(const float*)d_in[5], (const float*)d_in[8],
                       (const float*)d_in[11], (const float*)d_in[14]};

  // Workspace (125,829,120 B):
  //   combined @ 0          : 67,108,864
  //   Ut       @ 67,108,864 : 16,777,216
  //   Vt       @ 83,886,080 :  8,388,608
  //   Rbuf     @ 92,274,688 : 33,554,432
  char* ws = (char*)d_ws;
  bf16* combined = (bf16*)ws;
  bf16* Ut       = (bf16*)(ws + 67108864);
  bf16* Vt       = (bf16*)(ws + 67108864 + 16777216);
  bf16* Rbuf     = (bf16*)(ws + 67108864 + 16777216 + 8388608);

  float* hout = (float*)d_out;
  float* cout = hout + (size_t)BATCH * HID;

  k_convert_combined<<<(BATCH * (size_t)KDIM / 4) / 256, 256, 0, stream>>>(x, h, combined);

  k_tconv4<<<dim3(RANK / 32, KDIM / 32, 4), dim3(32, 8), 0, stream>>>(
      U[0], U[1], U[2], U[3], Ut, KDIM, RANK, KDIM, (long)RANK * KDIM);
  k_tconv4<<<dim3(HID / 32, RANK / 32, 4), dim3(32, 8), 0, stream>>>(
      V[0], V[1], V[2], V[3], Vt, RANK, HID, RANK, (long)HID * RANK);

  k_gemm1<<<256, 512, 0, stream>>>(combined, Ut, Rbuf);

  k_fused<<<256, 1024, 0, stream>>>(Rbuf, Vt, b[0], b[1], b[2], b[3], c, hout, cout);
}

// Round 9
// 343.631 us; speedup vs baseline: 3.4851x; 3.4851x over previous
//
#include <hip/hip_runtime.h>
#include <hip/hip_bf16.h>
#include <cstdint>
#include <cstddef>

typedef __bf16 bf16;
typedef __bf16 bf16x8 __attribute__((ext_vector_type(8)));
typedef float f32x4 __attribute__((ext_vector_type(4)));

#define BATCH 8192
#define IN_DIM 2048
#define HID 2048
#define RANK 512
#define KDIM 4096    // IN+HID
#define NG 2048      // 4*RANK
#define CHUNK_ROWS 4096

// ---------------- helpers ----------------

__device__ __forceinline__ void gload16(const void* g, void* l) {
  __builtin_amdgcn_global_load_lds(
      (const __attribute__((address_space(1))) unsigned int*)g,
      (__attribute__((address_space(3))) unsigned int*)l, 16, 0, 0);
}

__device__ __forceinline__ float sigmoidf_(float x) {
  return 1.0f / (1.0f + __expf(-x));
}
__device__ __forceinline__ float tanhf_(float x) {
  return 1.0f - 2.0f / (__expf(2.0f * x) + 1.0f);
}

#define GBAR  __builtin_amdgcn_s_barrier()
#define VMC4  asm volatile("s_waitcnt vmcnt(4)" ::: "memory")
#define VMC8  asm volatile("s_waitcnt vmcnt(8)" ::: "memory")
#define SB0   __builtin_amdgcn_sched_barrier(0)
#define LGKMC(N) do { asm volatile("s_waitcnt lgkmcnt(" #N ")" ::: "memory"); SB0; } while (0)

// Stage one 128x64 bf16 half-tile; inverse st-swizzle on GLOBAL source,
// LDS dest linear (both-sides rule). 512 thr x 2 x 16B. vmcnt += 2/thread.
__device__ __forceinline__ void stage_half(const bf16* __restrict__ g0, int ld,
                                           int row0, int kcol, bf16* lbase, int tid) {
  const int wid = tid >> 6;
  #pragma unroll
  for (int q = 0; q < 2; ++q) {
    const int slot = q * 512 + tid;
    const int row = slot >> 3, cb = slot & 7;
    const int gcb = cb ^ (row & 7);
    gload16(g0 + (size_t)(row0 + row) * ld + kcol + gcb * 8,
            lbase + (size_t)(q * 64 + wid * 8) * 64);
  }
}

// A-frag reads for quarter Q into parity set P (4 x ds_read_b128).
#define LD_APAR(PA, Q, P)                                                      \
  _Pragma("unroll") for (int ai = 0; ai < 2; ++ai)                             \
  _Pragma("unroll") for (int ks = 0; ks < 2; ++ks)                             \
    a[P][ai][ks] = *(const bf16x8*)((PA) + (wm + (Q) * 32 + ai * 16 + lr) * 64 \
                                 + ((((ks << 2) | lk) ^ sw) << 3));

// B-frag reads (8 x ds_read_b128).
#define LD_Bp(PB)                                                              \
  _Pragma("unroll") for (int j = 0; j < 4; ++j)                                \
  _Pragma("unroll") for (int ks = 0; ks < 2; ++ks)                             \
    b[j][ks] = *(const bf16x8*)((PB) + (wn + j * 16 + lr) * 64                 \
                                 + ((((ks << 2) | lk) ^ sw) << 3));

#define MFMAQP(Q, P)                                                           \
  _Pragma("unroll") for (int ai = 0; ai < 2; ++ai)                             \
  _Pragma("unroll") for (int ks = 0; ks < 2; ++ks)                             \
  _Pragma("unroll") for (int j = 0; j < 4; ++j)                                \
    acc[(Q) * 2 + ai][j] = __builtin_amdgcn_mfma_f32_16x16x32_bf16(            \
        a[P][ai][ks], b[j][ks], acc[(Q) * 2 + ai][j], 0, 0, 0);

// Counted-lgkm phase: issue next-phase reads BEFORE this phase's MFMA; single
// barrier; counted wait drains only this phase's reads so the next phase's
// reads service UNDER the MFMA cluster. Per-wave lgkm FIFO ledger:
//   Q0 entry [B(c)x8]; +A0,+A1 -> 16; wait 4 (drain B,A0; A1 in flight)
//   Q1 [A1]; +A2 -> 8; wait 4        (drain A1; A2 in flight)
//   Q2 [A2]; +A3 -> 8; wait 4        (drain A2; A3 in flight)
//   Q3 [A3]; wait 0; MFMA; +B(c+1)x8 (service under Q0's issue/stage window)
// Safety: all A reads target pAc (staged tile c-1, drained by every wave's
// VMC4 before the tile-entry barrier); B(c+1) staged tile c-2, drained by
// VMC4 at end of c-1 + barrier. Stage points & VMC4 identical to round 5.

template <int NT>
__device__ __forceinline__ void gemm_core(const bf16* __restrict__ A, int lda, int m0,
                                          const bf16* __restrict__ B, int ldb, int n0,
                                          bf16* lds, f32x4 (&acc)[8][4]) {
  const int tid = threadIdx.x;
  const int wid = tid >> 6, lane = tid & 63;
  const int wm = (wid >> 2) * 128, wn = (wid & 3) * 64;
  const int lr = lane & 15, lk = lane >> 4;
  const int sw = lr & 7;
  bf16x8 a[2][2][2];   // [parity][ai][ks]
  bf16x8 b[4][2];

  bf16* Ab0 = lds;
  bf16* Ab1 = lds + 16384;
  bf16* Rg0 = lds + 2 * 16384;
  bf16* Rg1 = lds + 3 * 16384;
  bf16* Rg2 = lds + 4 * 16384;

  #pragma unroll
  for (int i = 0; i < 8; ++i)
    #pragma unroll
    for (int j = 0; j < 4; ++j) acc[i][j] = (f32x4){0.f, 0.f, 0.f, 0.f};

  // Prologue (round-5 proven): A(0)->Ab0, B(0)->Rg0, B(1)->Rg1, B(2)->Rg2.
  stage_half(A, lda, m0,       0,   Ab0,        tid);
  stage_half(A, lda, m0 + 128, 0,   Ab0 + 8192, tid);
  stage_half(B, ldb, n0,       0,   Rg0,        tid);
  stage_half(B, ldb, n0 + 128, 0,   Rg0 + 8192, tid);
  stage_half(B, ldb, n0,       64,  Rg1,        tid);
  stage_half(B, ldb, n0 + 128, 64,  Rg1 + 8192, tid);
  stage_half(B, ldb, n0,       128, Rg2,        tid);
  stage_half(B, ldb, n0 + 128, 128, Rg2 + 8192, tid);
  VMC8;
  GBAR;
  LD_Bp(Rg0);   // B(0) -> 8 outstanding entering tile 0
  SB0;

  bf16 *pBc = Rg0, *pBn = Rg1, *pBn2 = Rg2;
  bf16 *pAc = Ab0, *pAa = Ab1;
  for (int c = 0; c < NT; ++c) {
    const int kc1 = ((c + 1) & (NT - 1)) * 64;
    const int kc3 = ((c + 3) & (NT - 1)) * 64;
    // ---- Q0 ----
    LD_APAR(pAc, 0, 0); LD_APAR(pAc, 1, 1); SB0;
    stage_half(A, lda, m0,       kc1, pAa,        tid); SB0;
    GBAR;
    LGKMC(4);
    __builtin_amdgcn_s_setprio(1); MFMAQP(0, 0); __builtin_amdgcn_s_setprio(0);
    // ---- Q1 ----
    LD_APAR(pAc, 2, 0); SB0;
    stage_half(A, lda, m0 + 128, kc1, pAa + 8192, tid); SB0;
    GBAR;
    LGKMC(4);
    __builtin_amdgcn_s_setprio(1); MFMAQP(1, 1); __builtin_amdgcn_s_setprio(0);
    // ---- Q2 ----
    LD_APAR(pAc, 3, 1); SB0;
    stage_half(B, ldb, n0,       kc3, pBc,        tid); SB0;
    GBAR;
    LGKMC(4);
    __builtin_amdgcn_s_setprio(1); MFMAQP(2, 0); __builtin_amdgcn_s_setprio(0);
    // ---- Q3 ----
    stage_half(B, ldb, n0 + 128, kc3, pBc + 8192, tid); SB0;
    VMC4;
    GBAR;
    LGKMC(0);
    __builtin_amdgcn_s_setprio(1); MFMAQP(3, 1); __builtin_amdgcn_s_setprio(0);
    LD_Bp(pBn);   // B(c+1) -> regs; services under next Q0 issue/stage window
    SB0;
    bf16* tt = pBc; pBc = pBn; pBn = pBn2; pBn2 = tt;
    tt = pAc; pAc = pAa; pAa = tt;
  }
}

// ---------------- convert & concat x,h -> bf16 combined [8192][4096] ----------------

__global__ void k_convert_combined(const float* __restrict__ x,
                                   const float* __restrict__ h,
                                   bf16* __restrict__ out) {
  size_t i4 = (size_t)blockIdx.x * blockDim.x + threadIdx.x;
  size_t base = i4 * 4;
  int col = (int)(base & (KDIM - 1));
  size_t row = base >> 12;
  const float* src = (col < IN_DIM) ? (x + row * IN_DIM + col)
                                    : (h + row * (size_t)HID + (col - IN_DIM));
  float4 v = *(const float4*)src;
  union { bf16 b[4]; uint2 u; } p;
  p.b[0] = (bf16)v.x; p.b[1] = (bf16)v.y; p.b[2] = (bf16)v.z; p.b[3] = (bf16)v.w;
  *(uint2*)(out + base) = p.u;
}

// ---------------- tiled transpose + convert, 4 gates per launch ----------------

__global__ void k_tconv4(const float* __restrict__ s0, const float* __restrict__ s1,
                         const float* __restrict__ s2, const float* __restrict__ s3,
                         bf16* __restrict__ out, int nrow, int ncol,
                         long ostride, long gstride) {
  __shared__ float t[32][33];
  const float* in = blockIdx.z == 0 ? s0 : blockIdx.z == 1 ? s1
                  : blockIdx.z == 2 ? s2 : s3;
  bf16* o = out + (size_t)blockIdx.z * gstride;
  int c0 = blockIdx.x * 32, r0 = blockIdx.y * 32;
  int tx = threadIdx.x, ty = threadIdx.y;
  #pragma unroll
  for (int yy = ty; yy < 32; yy += 8)
    t[yy][tx] = in[(size_t)(r0 + yy) * ncol + c0 + tx];
  __syncthreads();
  #pragma unroll
  for (int yy = ty; yy < 32; yy += 8)
    o[(size_t)(c0 + yy) * ostride + r0 + tx] = (bf16)t[tx][yy];
}

// ---------------- GEMM1: combined @ [Ui|Uf|Uc|Uo] -> R bf16 [8192][2048] ----------------

__launch_bounds__(512, 2)
__global__ void k_gemm1(const bf16* __restrict__ A,   // [8192][4096]
                        const bf16* __restrict__ Bt,  // [2048][4096]
                        bf16* __restrict__ R) {       // [8192][2048]
  __shared__ __align__(16) bf16 lds[81920];   // 160 KB
  const int bx = blockIdx.x;                  // 256 blocks
  const int id = (bx & 7) * 32 + (bx >> 3);   // XCD-bijective swizzle
  const int m0 = (id >> 3) * 256, n0 = (id & 7) * 256;
  f32x4 acc[8][4];
  gemm_core<KDIM / 64>(A, KDIM, m0, Bt, KDIM, n0, lds, acc);

  const int tid = threadIdx.x;
  const int wid = tid >> 6, lane = tid & 63;
  const int wm = (wid >> 2) * 128, wn = (wid & 3) * 64;
  const int lr = lane & 15, lk = lane >> 4;
  #pragma unroll
  for (int i = 0; i < 8; ++i)
    #pragma unroll
    for (int j = 0; j < 4; ++j)
      #pragma unroll
      for (int v = 0; v < 4; ++v)
        R[(size_t)(m0 + wm + i * 16 + lk * 4 + v) * NG + (n0 + wn + j * 16 + lr)] =
            (bf16)acc[i][j][v];
}

// ---------------- gate GEMMs + activation -> G bf16 [4][CHUNK_ROWS][HID] ----------------

__launch_bounds__(512, 2)
__global__ void k_gates(const bf16* __restrict__ Rb,   // [8192][2048]
                        const bf16* __restrict__ Vt,   // [4][2048][512]
                        const float* __restrict__ b0, const float* __restrict__ b1,
                        const float* __restrict__ b2, const float* __restrict__ b3,
                        bf16* __restrict__ G, int m_base) {
  __shared__ __align__(16) bf16 lds[81920];   // 160 KB
  const int bx = blockIdx.x;                  // 512 blocks
  const int id = (bx & 7) * 64 + (bx >> 3);   // XCD-bijective swizzle
  const int gate = id >> 7;                   // 0..3
  const int mo = ((id >> 3) & 15) * 256;      // row within chunk
  const int n0 = (id & 7) * 256;
  f32x4 acc[8][4];
  gemm_core<RANK / 64>(Rb + gate * RANK, NG, m_base + mo,
                       Vt + (size_t)gate * HID * RANK, RANK, n0, lds, acc);

  const int tid = threadIdx.x;
  const int wid = tid >> 6, lane = tid & 63;
  const int wm = (wid >> 2) * 128, wn = (wid & 3) * 64;
  const int lr = lane & 15, lk = lane >> 4;
  const float* bias = gate == 0 ? b0 : gate == 1 ? b1 : gate == 2 ? b2 : b3;
  const bool is_tanh = (gate == 2);
  bf16* Gg = G + (size_t)gate * CHUNK_ROWS * HID;
  #pragma unroll
  for (int j = 0; j < 4; ++j) {
    const int col = n0 + wn + j * 16 + lr;
    const float bj = bias[col];
    #pragma unroll
    for (int i = 0; i < 8; ++i)
      #pragma unroll
      for (int v = 0; v < 4; ++v) {
        const int row = mo + wm + i * 16 + lk * 4 + v;
        float p = acc[i][j][v] + bj;
        float av = is_tanh ? tanhf_(p) : sigmoidf_(p);
        Gg[(size_t)row * HID + col] = (bf16)av;
      }
  }
}

// ---------------- elementwise LSTM combine ----------------

__global__ void k_ew(const bf16* __restrict__ G,
                     const float* __restrict__ cin,
                     float* __restrict__ hout, float* __restrict__ cout,
                     int m_base) {
  const size_t CHUNK = (size_t)CHUNK_ROWS * HID;
  const bf16* Gi = G;
  const bf16* Gf = G + CHUNK;
  const bf16* Gc = G + 2 * CHUNK;
  const bf16* Go = G + 3 * CHUNK;
  const size_t n8 = CHUNK / 8;
  for (size_t t = (size_t)blockIdx.x * blockDim.x + threadIdx.x; t < n8;
       t += (size_t)gridDim.x * blockDim.x) {
    size_t e = t * 8;
    bf16x8 vi = *(const bf16x8*)(Gi + e);
    bf16x8 vf = *(const bf16x8*)(Gf + e);
    bf16x8 vc = *(const bf16x8*)(Gc + e);
    bf16x8 vo = *(const bf16x8*)(Go + e);
    size_t ge = (size_t)m_base * HID + e;
    float4 c0 = *(const float4*)(cin + ge);
    float4 c1 = *(const float4*)(cin + ge + 4);
    float cc[8] = {c0.x, c0.y, c0.z, c0.w, c1.x, c1.y, c1.z, c1.w};
    float cn[8], hn[8];
    #pragma unroll
    for (int v = 0; v < 8; ++v) {
      float iv = (float)vi[v], fv = (float)vf[v], cv = (float)vc[v], ov = (float)vo[v];
      cn[v] = fv * cc[v] + iv * cv;
      hn[v] = ov * tanhf_(cn[v]);
    }
    *(float4*)(cout + ge)     = (float4){cn[0], cn[1], cn[2], cn[3]};
    *(float4*)(cout + ge + 4) = (float4){cn[4], cn[5], cn[6], cn[7]};
    *(float4*)(hout + ge)     = (float4){hn[0], hn[1], hn[2], hn[3]};
    *(float4*)(hout + ge + 4) = (float4){hn[4], hn[5], hn[6], hn[7]};
  }
}

// ---------------- launch ----------------

extern "C" void kernel_launch(void* const* d_in, const int* in_sizes, int n_in,
                              void* d_out, int out_size, void* d_ws, size_t ws_size,
                              hipStream_t stream) {
  const float* x = (const float*)d_in[0];
  const float* h = (const float*)d_in[1];
  const float* c = (const float*)d_in[2];
  const float* U[4] = {(const float*)d_in[3], (const float*)d_in[6],
                       (const float*)d_in[9], (const float*)d_in[12]};
  const float* V[4] = {(const float*)d_in[4], (const float*)d_in[7],
                       (const float*)d_in[10], (const float*)d_in[13]};
  const float* b[4] = {(const float*)d_in[5], (const float*)d_in[8],
                       (const float*)d_in[11], (const float*)d_in[14]};

  // Workspace (125,829,120 B):
  //   combined @ 0          : 67,108,864   (aliased by G after gemm1)
  //   Ut       @ 67,108,864 : 16,777,216
  //   Vt       @ 83,886,080 :  8,388,608
  //   Rbuf     @ 92,274,688 : 33,554,432
  char* ws = (char*)d_ws;
  bf16* combined = (bf16*)ws;
  bf16* Ut       = (bf16*)(ws + 67108864);
  bf16* Vt       = (bf16*)(ws + 67108864 + 16777216);
  bf16* Rbuf     = (bf16*)(ws + 67108864 + 16777216 + 8388608);
  bf16* G        = (bf16*)ws;   // aliases combined

  float* hout = (float*)d_out;
  float* cout = hout + (size_t)BATCH * HID;

  k_convert_combined<<<(BATCH * (size_t)KDIM / 4) / 256, 256, 0, stream>>>(x, h, combined);

  k_tconv4<<<dim3(RANK / 32, KDIM / 32, 4), dim3(32, 8), 0, stream>>>(
      U[0], U[1], U[2], U[3], Ut, KDIM, RANK, KDIM, (long)RANK * KDIM);
  k_tconv4<<<dim3(HID / 32, RANK / 32, 4), dim3(32, 8), 0, stream>>>(
      V[0], V[1], V[2], V[3], Vt, RANK, HID, RANK, (long)HID * RANK);

  k_gemm1<<<256, 512, 0, stream>>>(combined, Ut, Rbuf);

  for (int chunk = 0; chunk < 2; ++chunk) {
    int m_base = chunk * CHUNK_ROWS;
    k_gates<<<512, 512, 0, stream>>>(Rbuf, Vt, b[0], b[1], b[2], b[3], G, m_base);
    k_ew<<<2048, 256, 0, stream>>>(G, c, hout, cout, m_base);
  }
}

// Round 10
// 332.324 us; speedup vs baseline: 3.6036x; 1.0340x over previous
//
#include <hip/hip_runtime.h>
#include <hip/hip_bf16.h>
#include <cstdint>
#include <cstddef>

typedef __bf16 bf16;
typedef __bf16 bf16x8 __attribute__((ext_vector_type(8)));
typedef float f32x4 __attribute__((ext_vector_type(4)));

#define BATCH 8192
#define IN_DIM 2048
#define HID 2048
#define RANK 512
#define KDIM 4096    // IN+HID
#define NG 2048      // 4*RANK

// ---------------- helpers ----------------

__device__ __forceinline__ void gload16(const void* g, void* l) {
  __builtin_amdgcn_global_load_lds(
      (const __attribute__((address_space(1))) unsigned int*)g,
      (__attribute__((address_space(3))) unsigned int*)l, 16, 0, 0);
}

__device__ __forceinline__ float sigmoidf_(float x) {
  return 1.0f / (1.0f + __expf(-x));
}
__device__ __forceinline__ float tanhf_(float x) {
  return 1.0f - 2.0f / (__expf(2.0f * x) + 1.0f);
}

#define GBAR  __builtin_amdgcn_s_barrier()
#define VMC0  asm volatile("s_waitcnt vmcnt(0)" ::: "memory")
#define VMC2  asm volatile("s_waitcnt vmcnt(2)" ::: "memory")
#define VMC4  asm volatile("s_waitcnt vmcnt(4)" ::: "memory")
#define VMC8  asm volatile("s_waitcnt vmcnt(8)" ::: "memory")
#define SB0   __builtin_amdgcn_sched_barrier(0)
#define LGKMC(N) do { asm volatile("s_waitcnt lgkmcnt(" #N ")" ::: "memory"); SB0; } while (0)

// Stage one 128x64 bf16 half-tile; inverse st-swizzle on GLOBAL source,
// LDS dest linear (both-sides rule). 512 thr x 2 x 16B. vmcnt += 2/thread.
__device__ __forceinline__ void stage_half(const bf16* __restrict__ g0, int ld,
                                           int row0, int kcol, bf16* lbase, int tid) {
  const int wid = tid >> 6;
  #pragma unroll
  for (int q = 0; q < 2; ++q) {
    const int slot = q * 512 + tid;
    const int row = slot >> 3, cb = slot & 7;
    const int gcb = cb ^ (row & 7);
    gload16(g0 + (size_t)(row0 + row) * ld + kcol + gcb * 8,
            lbase + (size_t)(q * 64 + wid * 8) * 64);
  }
}

// B-frag reads (8 x ds_read_b128).
#define LD_Bp(PB)                                                              \
  _Pragma("unroll") for (int j = 0; j < 4; ++j)                                \
  _Pragma("unroll") for (int ks = 0; ks < 2; ++ks)                             \
    b[j][ks] = *(const bf16x8*)((PB) + (wn + j * 16 + lr) * 64                 \
                                 + ((((ks << 2) | lk) ^ sw) << 3));

// =============== 512-thread 256x256 core (k_gemm1) — round-9 proven ===============

#define LD_APAR(PA, Q, P)                                                      \
  _Pragma("unroll") for (int ai = 0; ai < 2; ++ai)                             \
  _Pragma("unroll") for (int ks = 0; ks < 2; ++ks)                             \
    a[P][ai][ks] = *(const bf16x8*)((PA) + (wm + (Q) * 32 + ai * 16 + lr) * 64 \
                                 + ((((ks << 2) | lk) ^ sw) << 3));

#define MFMAQP(Q, P)                                                           \
  _Pragma("unroll") for (int ai = 0; ai < 2; ++ai)                             \
  _Pragma("unroll") for (int ks = 0; ks < 2; ++ks)                             \
  _Pragma("unroll") for (int j = 0; j < 4; ++j)                                \
    acc[(Q) * 2 + ai][j] = __builtin_amdgcn_mfma_f32_16x16x32_bf16(            \
        a[P][ai][ks], b[j][ks], acc[(Q) * 2 + ai][j], 0, 0, 0);

template <int NT>
__device__ __forceinline__ void gemm_core(const bf16* __restrict__ A, int lda, int m0,
                                          const bf16* __restrict__ B, int ldb, int n0,
                                          bf16* lds, f32x4 (&acc)[8][4]) {
  const int tid = threadIdx.x;
  const int wid = tid >> 6, lane = tid & 63;
  const int wm = (wid >> 2) * 128, wn = (wid & 3) * 64;
  const int lr = lane & 15, lk = lane >> 4;
  const int sw = lr & 7;
  bf16x8 a[2][2][2];   // [parity][ai][ks]
  bf16x8 b[4][2];

  bf16* Ab0 = lds;
  bf16* Ab1 = lds + 16384;
  bf16* Rg0 = lds + 2 * 16384;
  bf16* Rg1 = lds + 3 * 16384;
  bf16* Rg2 = lds + 4 * 16384;

  #pragma unroll
  for (int i = 0; i < 8; ++i)
    #pragma unroll
    for (int j = 0; j < 4; ++j) acc[i][j] = (f32x4){0.f, 0.f, 0.f, 0.f};

  stage_half(A, lda, m0,       0,   Ab0,        tid);
  stage_half(A, lda, m0 + 128, 0,   Ab0 + 8192, tid);
  stage_half(B, ldb, n0,       0,   Rg0,        tid);
  stage_half(B, ldb, n0 + 128, 0,   Rg0 + 8192, tid);
  stage_half(B, ldb, n0,       64,  Rg1,        tid);
  stage_half(B, ldb, n0 + 128, 64,  Rg1 + 8192, tid);
  stage_half(B, ldb, n0,       128, Rg2,        tid);
  stage_half(B, ldb, n0 + 128, 128, Rg2 + 8192, tid);
  VMC8;
  GBAR;
  LD_Bp(Rg0);
  SB0;

  bf16 *pBc = Rg0, *pBn = Rg1, *pBn2 = Rg2;
  bf16 *pAc = Ab0, *pAa = Ab1;
  for (int c = 0; c < NT; ++c) {
    const int kc1 = ((c + 1) & (NT - 1)) * 64;
    const int kc3 = ((c + 3) & (NT - 1)) * 64;
    // ---- Q0 ----
    LD_APAR(pAc, 0, 0); LD_APAR(pAc, 1, 1); SB0;
    stage_half(A, lda, m0,       kc1, pAa,        tid); SB0;
    GBAR;
    LGKMC(4);
    __builtin_amdgcn_s_setprio(1); MFMAQP(0, 0); __builtin_amdgcn_s_setprio(0);
    // ---- Q1 ----
    LD_APAR(pAc, 2, 0); SB0;
    stage_half(A, lda, m0 + 128, kc1, pAa + 8192, tid); SB0;
    GBAR;
    LGKMC(4);
    __builtin_amdgcn_s_setprio(1); MFMAQP(1, 1); __builtin_amdgcn_s_setprio(0);
    // ---- Q2 ----
    LD_APAR(pAc, 3, 1); SB0;
    stage_half(B, ldb, n0,       kc3, pBc,        tid); SB0;
    GBAR;
    LGKMC(4);
    __builtin_amdgcn_s_setprio(1); MFMAQP(2, 0); __builtin_amdgcn_s_setprio(0);
    // ---- Q3 ----
    stage_half(B, ldb, n0 + 128, kc3, pBc + 8192, tid); SB0;
    VMC4;
    GBAR;
    LGKMC(0);
    __builtin_amdgcn_s_setprio(1); MFMAQP(3, 1); __builtin_amdgcn_s_setprio(0);
    LD_Bp(pBn);
    SB0;
    bf16* tt = pBc; pBc = pBn; pBn = pBn2; pBn2 = tt;
    tt = pAc; pAc = pAa; pAa = tt;
  }
}

// =============== 512-thread 256x128 pair core (k_pair_*) ===============
// 8 waves (4M x 2N); wave = 64x64; acc[4][4] = 64 regs per gate. One gate per
// call; caller carries the other gate's acc in AGPRs. LDS 112 KB:
// A dbuf 2x32KB + B ring 3x16KB. Stages/K-tile: A h0 (Q0), A h1 (Q1), B (Q2).
// vmcnt: prologue 10 loads -> VMC4; steady VMC2 at Q3 (leaves B(c+3) only).
// lgkm: counted 2/2/2/0 with 2-read parity sets; Q3 lgkm0 BEFORE barrier
// (closes the cross-wave A-read-vs-restage window).

#define LD_AP(PA, Q, P)                                                        \
  _Pragma("unroll") for (int ks = 0; ks < 2; ++ks)                             \
    ap[P][ks] = *(const bf16x8*)((PA) + (wm + (Q) * 16 + lr) * 64              \
                                 + ((((ks << 2) | lk) ^ sw) << 3));

#define MFMAP(Q, P)                                                            \
  _Pragma("unroll") for (int ks = 0; ks < 2; ++ks)                             \
  _Pragma("unroll") for (int j = 0; j < 4; ++j)                                \
    acc[(Q)][j] = __builtin_amdgcn_mfma_f32_16x16x32_bf16(                     \
        ap[P][ks], b[j][ks], acc[(Q)][j], 0, 0, 0);

template <int NT>
__device__ __forceinline__ void gemm_coreP(const bf16* __restrict__ A, int lda, int m0,
                                           const bf16* __restrict__ B, int ldb, int n0,
                                           bf16* lds, f32x4 (&acc)[4][4]) {
  const int tid = threadIdx.x;
  const int wid = tid >> 6, lane = tid & 63;
  const int wm = (wid >> 1) * 64, wn = (wid & 1) * 64;
  const int lr = lane & 15, lk = lane >> 4;
  const int sw = lr & 7;
  bf16x8 ap[2][2], b[4][2];

  bf16* Ab0 = lds;
  bf16* Ab1 = lds + 16384;
  bf16* Rg0 = lds + 32768;
  bf16* Rg1 = lds + 40960;
  bf16* Rg2 = lds + 49152;

  #pragma unroll
  for (int i = 0; i < 4; ++i)
    #pragma unroll
    for (int j = 0; j < 4; ++j) acc[i][j] = (f32x4){0.f, 0.f, 0.f, 0.f};

  // Prologue: A(0) 2SH, B(0),B(1),B(2) 1SH each = 10 loads/thread.
  stage_half(A, lda, m0,       0,   Ab0,        tid);
  stage_half(A, lda, m0 + 128, 0,   Ab0 + 8192, tid);
  stage_half(B, ldb, n0, 0,   Rg0, tid);
  stage_half(B, ldb, n0, 64,  Rg1, tid);
  stage_half(B, ldb, n0, 128, Rg2, tid);
  VMC4;   // A(0),B(0) drained; B(1),B(2) in flight
  GBAR;
  LD_Bp(Rg0);
  SB0;

  bf16 *pBc = Rg0, *pBn = Rg1, *pBn2 = Rg2;
  bf16 *pAc = Ab0, *pAa = Ab1;
  for (int c = 0; c < NT; ++c) {
    const int kc1 = ((c + 1) & (NT - 1)) * 64;
    const int kc3 = ((c + 3) & (NT - 1)) * 64;
    // ---- Q0 ----  lgkm FIFO: [B 8] +A0(2) +A1(2) -> wait 2 drains B,A0
    LD_AP(pAc, 0, 0); LD_AP(pAc, 1, 1); SB0;
    stage_half(A, lda, m0,       kc1, pAa,        tid); SB0;
    GBAR;
    LGKMC(2);
    __builtin_amdgcn_s_setprio(1); MFMAP(0, 0); __builtin_amdgcn_s_setprio(0);
    // ---- Q1 ----  [A1] +A2 -> wait 2 drains A1
    LD_AP(pAc, 2, 0); SB0;
    stage_half(A, lda, m0 + 128, kc1, pAa + 8192, tid); SB0;
    GBAR;
    LGKMC(2);
    __builtin_amdgcn_s_setprio(1); MFMAP(1, 1); __builtin_amdgcn_s_setprio(0);
    // ---- Q2 ----  [A2] +A3 -> wait 2 drains A2
    LD_AP(pAc, 3, 1); SB0;
    stage_half(B, ldb, n0, kc3, pBc, tid); SB0;
    GBAR;
    LGKMC(2);
    __builtin_amdgcn_s_setprio(1); MFMAP(2, 0); __builtin_amdgcn_s_setprio(0);
    // ---- Q3 ----  drain A3 + own stage loads BEFORE barrier
    VMC2;
    LGKMC(0);
    GBAR;
    __builtin_amdgcn_s_setprio(1); MFMAP(3, 1); __builtin_amdgcn_s_setprio(0);
    LD_Bp(pBn);   // B(c+1) -> regs, services under next Q0 window
    SB0;
    bf16* tt = pBc; pBc = pBn; pBn = pBn2; pBn2 = tt;
    tt = pAc; pAc = pAa; pAa = tt;
  }
}

// ---------------- convert & concat x,h -> bf16 combined [8192][4096] ----------------

__global__ void k_convert_combined(const float* __restrict__ x,
                                   const float* __restrict__ h,
                                   bf16* __restrict__ out) {
  size_t i4 = (size_t)blockIdx.x * blockDim.x + threadIdx.x;
  size_t base = i4 * 4;
  int col = (int)(base & (KDIM - 1));
  size_t row = base >> 12;
  const float* src = (col < IN_DIM) ? (x + row * IN_DIM + col)
                                    : (h + row * (size_t)HID + (col - IN_DIM));
  float4 v = *(const float4*)src;
  union { bf16 b[4]; uint2 u; } p;
  p.b[0] = (bf16)v.x; p.b[1] = (bf16)v.y; p.b[2] = (bf16)v.z; p.b[3] = (bf16)v.w;
  *(uint2*)(out + base) = p.u;
}

// ---------------- tiled transpose + convert, 4 gates per launch ----------------

__global__ void k_tconv4(const float* __restrict__ s0, const float* __restrict__ s1,
                         const float* __restrict__ s2, const float* __restrict__ s3,
                         bf16* __restrict__ out, int nrow, int ncol,
                         long ostride, long gstride) {
  __shared__ float t[32][33];
  const float* in = blockIdx.z == 0 ? s0 : blockIdx.z == 1 ? s1
                  : blockIdx.z == 2 ? s2 : s3;
  bf16* o = out + (size_t)blockIdx.z * gstride;
  int c0 = blockIdx.x * 32, r0 = blockIdx.y * 32;
  int tx = threadIdx.x, ty = threadIdx.y;
  #pragma unroll
  for (int yy = ty; yy < 32; yy += 8)
    t[yy][tx] = in[(size_t)(r0 + yy) * ncol + c0 + tx];
  __syncthreads();
  #pragma unroll
  for (int yy = ty; yy < 32; yy += 8)
    o[(size_t)(c0 + yy) * ostride + r0 + tx] = (bf16)t[tx][yy];
}

// ---------------- GEMM1: combined @ [Ui|Uf|Uc|Uo] -> R bf16 [8192][2048] ----------------

__launch_bounds__(512, 2)
__global__ void k_gemm1(const bf16* __restrict__ A,   // [8192][4096]
                        const bf16* __restrict__ Bt,  // [2048][4096]
                        bf16* __restrict__ R) {       // [8192][2048]
  __shared__ __align__(16) bf16 lds[81920];   // 160 KB
  const int bx = blockIdx.x;                  // 256 blocks
  const int id = (bx & 7) * 32 + (bx >> 3);   // XCD-bijective swizzle
  const int m0 = (id >> 3) * 256, n0 = (id & 7) * 256;
  f32x4 acc[8][4];
  gemm_core<KDIM / 64>(A, KDIM, m0, Bt, KDIM, n0, lds, acc);

  const int tid = threadIdx.x;
  const int wid = tid >> 6, lane = tid & 63;
  const int wm = (wid >> 2) * 128, wn = (wid & 3) * 64;
  const int lr = lane & 15, lk = lane >> 4;
  #pragma unroll
  for (int i = 0; i < 8; ++i)
    #pragma unroll
    for (int j = 0; j < 4; ++j)
      #pragma unroll
      for (int v = 0; v < 4; ++v)
        R[(size_t)(m0 + wm + i * 16 + lk * 4 + v) * NG + (n0 + wn + j * 16 + lr)] =
            (bf16)acc[i][j][v];
}

// ---------------- pair kernel 1: gates i,c -> sv = sigmoid(i)*tanh(c) ----------------

__launch_bounds__(512, 2)
__global__ void k_pair_ic(const bf16* __restrict__ Rb,   // [8192][2048]
                          const bf16* __restrict__ Vt,   // [4][2048][512]
                          const float* __restrict__ bi, const float* __restrict__ bc,
                          bf16* __restrict__ sv) {       // [8192][2048]
  __shared__ __align__(16) bf16 lds[57344];   // 112 KB
  const int bx = blockIdx.x;                  // 512 blocks
  const int id = (bx & 7) * 64 + (bx >> 3);   // XCD-bijective swizzle
  const int m0 = (id >> 4) * 256, n0 = (id & 15) * 128;

  f32x4 accI[4][4], accC[4][4];
  gemm_coreP<RANK / 64>(Rb + 0 * RANK, NG, m0,
                        Vt + (size_t)0 * HID * RANK, RANK, n0, lds, accI);
  VMC0;   // drain wrapped tail DMAs before restaging same LDS (WAW order)
  GBAR;
  gemm_coreP<RANK / 64>(Rb + 2 * RANK, NG, m0,
                        Vt + (size_t)2 * HID * RANK, RANK, n0, lds, accC);

  const int tid = threadIdx.x;
  const int wid = tid >> 6, lane = tid & 63;
  const int wm = (wid >> 1) * 64, wn = (wid & 1) * 64;
  const int lr = lane & 15, lk = lane >> 4;
  #pragma unroll
  for (int j = 0; j < 4; ++j) {
    const int col = n0 + wn + j * 16 + lr;
    const float bji = bi[col], bjc = bc[col];
    #pragma unroll
    for (int q = 0; q < 4; ++q)
      #pragma unroll
      for (int v = 0; v < 4; ++v) {
        const int row = m0 + wm + q * 16 + lk * 4 + v;
        const float s = sigmoidf_(accI[q][j][v] + bji) * tanhf_(accC[q][j][v] + bjc);
        sv[(size_t)row * HID + col] = (bf16)s;
      }
  }
}

// ---------------- pair kernel 2: gates f,o + final LSTM combine ----------------

__launch_bounds__(512, 2)
__global__ void k_pair_fo(const bf16* __restrict__ Rb,   // [8192][2048]
                          const bf16* __restrict__ Vt,   // [4][2048][512]
                          const float* __restrict__ bf_, const float* __restrict__ bo,
                          const bf16* __restrict__ sv,   // [8192][2048]
                          const float* __restrict__ cin, // [8192][2048]
                          float* __restrict__ hout, float* __restrict__ cout) {
  __shared__ __align__(16) bf16 lds[57344];   // 112 KB
  const int bx = blockIdx.x;                  // 512 blocks
  const int id = (bx & 7) * 64 + (bx >> 3);   // XCD-bijective swizzle
  const int m0 = (id >> 4) * 256, n0 = (id & 15) * 128;

  f32x4 accF[4][4], accO[4][4];
  gemm_coreP<RANK / 64>(Rb + 1 * RANK, NG, m0,
                        Vt + (size_t)1 * HID * RANK, RANK, n0, lds, accF);
  VMC0;
  GBAR;
  gemm_coreP<RANK / 64>(Rb + 3 * RANK, NG, m0,
                        Vt + (size_t)3 * HID * RANK, RANK, n0, lds, accO);

  const int tid = threadIdx.x;
  const int wid = tid >> 6, lane = tid & 63;
  const int wm = (wid >> 1) * 64, wn = (wid & 1) * 64;
  const int lr = lane & 15, lk = lane >> 4;
  #pragma unroll
  for (int j = 0; j < 4; ++j) {
    const int col = n0 + wn + j * 16 + lr;
    const float bjf = bf_[col], bjo = bo[col];
    #pragma unroll
    for (int q = 0; q < 4; ++q)
      #pragma unroll
      for (int v = 0; v < 4; ++v) {
        const int row = m0 + wm + q * 16 + lk * 4 + v;
        const size_t e = (size_t)row * HID + col;
        const float f = sigmoidf_(accF[q][j][v] + bjf);
        const float cn = f * cin[e] + (float)sv[e];
        cout[e] = cn;
        hout[e] = sigmoidf_(accO[q][j][v] + bjo) * tanhf_(cn);
      }
  }
}

// ---------------- launch ----------------

extern "C" void kernel_launch(void* const* d_in, const int* in_sizes, int n_in,
                              void* d_out, int out_size, void* d_ws, size_t ws_size,
                              hipStream_t stream) {
  const float* x = (const float*)d_in[0];
  const float* h = (const float*)d_in[1];
  const float* c = (const float*)d_in[2];
  const float* U[4] = {(const float*)d_in[3], (const float*)d_in[6],
                       (const float*)d_in[9], (const float*)d_in[12]};
  const float* V[4] = {(const float*)d_in[4], (const float*)d_in[7],
                       (const float*)d_in[10], (const float*)d_in[13]};
  const float* b[4] = {(const float*)d_in[5], (const float*)d_in[8],
                       (const float*)d_in[11], (const float*)d_in[14]};

  // Workspace (125,829,120 B):
  //   combined @ 0          : 67,108,864   (sv [33.5 MB] aliases it after gemm1)
  //   Ut       @ 67,108,864 : 16,777,216
  //   Vt       @ 83,886,080 :  8,388,608
  //   Rbuf     @ 92,274,688 : 33,554,432
  char* ws = (char*)d_ws;
  bf16* combined = (bf16*)ws;
  bf16* Ut       = (bf16*)(ws + 67108864);
  bf16* Vt       = (bf16*)(ws + 67108864 + 16777216);
  bf16* Rbuf     = (bf16*)(ws + 67108864 + 16777216 + 8388608);
  bf16* sv       = (bf16*)ws;   // aliases combined (dead after gemm1)

  float* hout = (float*)d_out;
  float* cout = hout + (size_t)BATCH * HID;

  k_convert_combined<<<(BATCH * (size_t)KDIM / 4) / 256, 256, 0, stream>>>(x, h, combined);

  k_tconv4<<<dim3(RANK / 32, KDIM / 32, 4), dim3(32, 8), 0, stream>>>(
      U[0], U[1], U[2], U[3], Ut, KDIM, RANK, KDIM, (long)RANK * KDIM);
  k_tconv4<<<dim3(HID / 32, RANK / 32, 4), dim3(32, 8), 0, stream>>>(
      V[0], V[1], V[2], V[3], Vt, RANK, HID, RANK, (long)HID * RANK);

  k_gemm1<<<256, 512, 0, stream>>>(combined, Ut, Rbuf);

  k_pair_ic<<<512, 512, 0, stream>>>(Rbuf, Vt, b[0], b[2], sv);
  k_pair_fo<<<512, 512, 0, stream>>>(Rbuf, Vt, b[1], b[3], sv, c, hout, cout);
}

// Round 11
// 319.765 us; speedup vs baseline: 3.7452x; 1.0393x over previous
//
#include <hip/hip_runtime.h>
#include <hip/hip_bf16.h>
#include <cstdint>
#include <cstddef>

typedef __bf16 bf16;
typedef __bf16 bf16x8 __attribute__((ext_vector_type(8)));
typedef float f32x4 __attribute__((ext_vector_type(4)));

#define BATCH 8192
#define IN_DIM 2048
#define HID 2048
#define RANK 512
#define KDIM 4096    // IN+HID
#define NG 2048      // 4*RANK

// ---------------- helpers ----------------

__device__ __forceinline__ void gload16(const void* g, void* l) {
  __builtin_amdgcn_global_load_lds(
      (const __attribute__((address_space(1))) unsigned int*)g,
      (__attribute__((address_space(3))) unsigned int*)l, 16, 0, 0);
}

__device__ __forceinline__ float sigmoidf_(float x) {
  return 1.0f / (1.0f + __expf(-x));
}
__device__ __forceinline__ float tanhf_(float x) {
  return 1.0f - 2.0f / (__expf(2.0f * x) + 1.0f);
}

#define GBAR  __builtin_amdgcn_s_barrier()
#define VMC2  asm volatile("s_waitcnt vmcnt(2)" ::: "memory")
#define VMC4  asm volatile("s_waitcnt vmcnt(4)" ::: "memory")
#define VMC8  asm volatile("s_waitcnt vmcnt(8)" ::: "memory")
#define SB0   __builtin_amdgcn_sched_barrier(0)
#define LGKMC(N) do { asm volatile("s_waitcnt lgkmcnt(" #N ")" ::: "memory"); SB0; } while (0)

// Stage one 128x64 bf16 half-tile; inverse st-swizzle on GLOBAL source,
// LDS dest linear (both-sides rule). 512 thr x 2 x 16B. vmcnt += 2/thread.
__device__ __forceinline__ void stage_half(const bf16* __restrict__ g0, int ld,
                                           int row0, int kcol, bf16* lbase, int tid) {
  const int wid = tid >> 6;
  #pragma unroll
  for (int q = 0; q < 2; ++q) {
    const int slot = q * 512 + tid;
    const int row = slot >> 3, cb = slot & 7;
    const int gcb = cb ^ (row & 7);
    gload16(g0 + (size_t)(row0 + row) * ld + kcol + gcb * 8,
            lbase + (size_t)(q * 64 + wid * 8) * 64);
  }
}

// B-frag reads (8 x ds_read_b128).
#define LD_Bp(PB)                                                              \
  _Pragma("unroll") for (int j = 0; j < 4; ++j)                                \
  _Pragma("unroll") for (int ks = 0; ks < 2; ++ks)                             \
    b[j][ks] = *(const bf16x8*)((PB) + (wn + j * 16 + lr) * 64                 \
                                 + ((((ks << 2) | lk) ^ sw) << 3));

// =============== 512-thread 256x256 core (k_gemm1) — round-9 proven ===============

#define LD_APAR(PA, Q, P)                                                      \
  _Pragma("unroll") for (int ai = 0; ai < 2; ++ai)                             \
  _Pragma("unroll") for (int ks = 0; ks < 2; ++ks)                             \
    a[P][ai][ks] = *(const bf16x8*)((PA) + (wm + (Q) * 32 + ai * 16 + lr) * 64 \
                                 + ((((ks << 2) | lk) ^ sw) << 3));

#define MFMAQP(Q, P)                                                           \
  _Pragma("unroll") for (int ai = 0; ai < 2; ++ai)                             \
  _Pragma("unroll") for (int ks = 0; ks < 2; ++ks)                             \
  _Pragma("unroll") for (int j = 0; j < 4; ++j)                                \
    acc[(Q) * 2 + ai][j] = __builtin_amdgcn_mfma_f32_16x16x32_bf16(            \
        a[P][ai][ks], b[j][ks], acc[(Q) * 2 + ai][j], 0, 0, 0);

template <int NT>
__device__ __forceinline__ void gemm_core(const bf16* __restrict__ A, int lda, int m0,
                                          const bf16* __restrict__ B, int ldb, int n0,
                                          bf16* lds, f32x4 (&acc)[8][4]) {
  const int tid = threadIdx.x;
  const int wid = tid >> 6, lane = tid & 63;
  const int wm = (wid >> 2) * 128, wn = (wid & 3) * 64;
  const int lr = lane & 15, lk = lane >> 4;
  const int sw = lr & 7;
  bf16x8 a[2][2][2];   // [parity][ai][ks]
  bf16x8 b[4][2];

  bf16* Ab0 = lds;
  bf16* Ab1 = lds + 16384;
  bf16* Rg0 = lds + 2 * 16384;
  bf16* Rg1 = lds + 3 * 16384;
  bf16* Rg2 = lds + 4 * 16384;

  #pragma unroll
  for (int i = 0; i < 8; ++i)
    #pragma unroll
    for (int j = 0; j < 4; ++j) acc[i][j] = (f32x4){0.f, 0.f, 0.f, 0.f};

  stage_half(A, lda, m0,       0,   Ab0,        tid);
  stage_half(A, lda, m0 + 128, 0,   Ab0 + 8192, tid);
  stage_half(B, ldb, n0,       0,   Rg0,        tid);
  stage_half(B, ldb, n0 + 128, 0,   Rg0 + 8192, tid);
  stage_half(B, ldb, n0,       64,  Rg1,        tid);
  stage_half(B, ldb, n0 + 128, 64,  Rg1 + 8192, tid);
  stage_half(B, ldb, n0,       128, Rg2,        tid);
  stage_half(B, ldb, n0 + 128, 128, Rg2 + 8192, tid);
  VMC8;
  GBAR;
  LD_Bp(Rg0);
  SB0;

  bf16 *pBc = Rg0, *pBn = Rg1, *pBn2 = Rg2;
  bf16 *pAc = Ab0, *pAa = Ab1;
  for (int c = 0; c < NT; ++c) {
    const int kc1 = ((c + 1) & (NT - 1)) * 64;
    const int kc3 = ((c + 3) & (NT - 1)) * 64;
    // ---- Q0 ----
    LD_APAR(pAc, 0, 0); LD_APAR(pAc, 1, 1); SB0;
    stage_half(A, lda, m0,       kc1, pAa,        tid); SB0;
    GBAR;
    LGKMC(4);
    __builtin_amdgcn_s_setprio(1); MFMAQP(0, 0); __builtin_amdgcn_s_setprio(0);
    // ---- Q1 ----
    LD_APAR(pAc, 2, 0); SB0;
    stage_half(A, lda, m0 + 128, kc1, pAa + 8192, tid); SB0;
    GBAR;
    LGKMC(4);
    __builtin_amdgcn_s_setprio(1); MFMAQP(1, 1); __builtin_amdgcn_s_setprio(0);
    // ---- Q2 ----
    LD_APAR(pAc, 3, 1); SB0;
    stage_half(B, ldb, n0,       kc3, pBc,        tid); SB0;
    GBAR;
    LGKMC(4);
    __builtin_amdgcn_s_setprio(1); MFMAQP(2, 0); __builtin_amdgcn_s_setprio(0);
    // ---- Q3 ----
    stage_half(B, ldb, n0 + 128, kc3, pBc + 8192, tid); SB0;
    VMC4;
    GBAR;
    LGKMC(0);
    __builtin_amdgcn_s_setprio(1); MFMAQP(3, 1); __builtin_amdgcn_s_setprio(0);
    LD_Bp(pBn);
    SB0;
    bf16* tt = pBc; pBc = pBn; pBn = pBn2; pBn2 = tt;
    tt = pAc; pAc = pAa; pAa = tt;
  }
}

// =============== 512-thread 256x128 DUAL-GATE interleaved core ===============
// 8 waves (4M x 2N); wave = 64x64 per gate; accA+accB = 128 regs (the proven
// budget at 2 waves/SIMD). 2*NT steps alternate gate A / gate B; per-step
// quarter skeleton, staging points, lgkm ledger (2/2/2/0) and vmcnt ledger
// (prologue 10 loads -> VMC4; steady VMC2 at Q3) are identical to the r10
// passing core — only stage source addresses depend on step parity.
// LDS 112 KB: A dbuf 2x32KB + B ring 3x16KB.

#define LD_AP(PA, Q, P)                                                        \
  _Pragma("unroll") for (int ks = 0; ks < 2; ++ks)                             \
    ap[P][ks] = *(const bf16x8*)((PA) + (wm + (Q) * 16 + lr) * 64              \
                                 + ((((ks << 2) | lk) ^ sw) << 3));

#define MFMAP2(ACC, Q, P)                                                      \
  _Pragma("unroll") for (int ks = 0; ks < 2; ++ks)                             \
  _Pragma("unroll") for (int j = 0; j < 4; ++j)                                \
    ACC[(Q)][j] = __builtin_amdgcn_mfma_f32_16x16x32_bf16(                     \
        ap[P][ks], b[j][ks], ACC[(Q)][j], 0, 0, 0);

// One step: consume current A/B LDS tiles into ACC; stage A for step s+1
// (Rb col ACOL) and B for step s+3 (BPTR col BCOL).
#define STEP2(ACC, ACOL, BPTR, BCOL)                                           \
  {                                                                            \
    LD_AP(pAc, 0, 0); LD_AP(pAc, 1, 1); SB0;                                   \
    stage_half(Rb, lda, m0,       (ACOL), pAa,        tid); SB0;               \
    GBAR;                                                                      \
    LGKMC(2);                                                                  \
    __builtin_amdgcn_s_setprio(1); MFMAP2(ACC, 0, 0); __builtin_amdgcn_s_setprio(0); \
    LD_AP(pAc, 2, 0); SB0;                                                     \
    stage_half(Rb, lda, m0 + 128, (ACOL), pAa + 8192, tid); SB0;               \
    GBAR;                                                                      \
    LGKMC(2);                                                                  \
    __builtin_amdgcn_s_setprio(1); MFMAP2(ACC, 1, 1); __builtin_amdgcn_s_setprio(0); \
    LD_AP(pAc, 3, 1); SB0;                                                     \
    stage_half((BPTR), ldb, n0, (BCOL), pBc, tid); SB0;                        \
    GBAR;                                                                      \
    LGKMC(2);                                                                  \
    __builtin_amdgcn_s_setprio(1); MFMAP2(ACC, 2, 0); __builtin_amdgcn_s_setprio(0); \
    VMC2;                                                                      \
    LGKMC(0);                                                                  \
    GBAR;                                                                      \
    __builtin_amdgcn_s_setprio(1); MFMAP2(ACC, 3, 1); __builtin_amdgcn_s_setprio(0); \
    LD_Bp(pBn);                                                                \
    SB0;                                                                       \
    bf16* tt_ = pBc; pBc = pBn; pBn = pBn2; pBn2 = tt_;                        \
    tt_ = pAc; pAc = pAa; pAa = tt_;                                           \
  }

template <int NT>   // K-tiles per gate (RANK/64 = 8)
__device__ __forceinline__ void gemm_coreP2(
    const bf16* __restrict__ Rb, int lda, int m0, int kgA, int kgB,
    const bf16* __restrict__ VA, const bf16* __restrict__ VB, int ldb, int n0,
    bf16* lds, f32x4 (&accA)[4][4], f32x4 (&accB)[4][4]) {
  const int tid = threadIdx.x;
  const int wid = tid >> 6, lane = tid & 63;
  const int wm = (wid >> 1) * 64, wn = (wid & 1) * 64;
  const int lr = lane & 15, lk = lane >> 4;
  const int sw = lr & 7;
  bf16x8 ap[2][2], b[4][2];

  bf16* Ab0 = lds;
  bf16* Ab1 = lds + 16384;
  bf16* Rg0 = lds + 32768;
  bf16* Rg1 = lds + 40960;
  bf16* Rg2 = lds + 49152;

  #pragma unroll
  for (int i = 0; i < 4; ++i)
    #pragma unroll
    for (int j = 0; j < 4; ++j) {
      accA[i][j] = (f32x4){0.f, 0.f, 0.f, 0.f};
      accB[i][j] = (f32x4){0.f, 0.f, 0.f, 0.f};
    }

  // Prologue: A(step0 = gate A, tile 0) 2SH; B for steps 0,1,2 = VA(0), VB(0),
  // VA(64). 10 loads/thread; VMC4 drains A(0)+B(0), leaves B(1),B(2).
  stage_half(Rb, lda, m0,       kgA, Ab0,        tid);
  stage_half(Rb, lda, m0 + 128, kgA, Ab0 + 8192, tid);
  stage_half(VA, ldb, n0, 0,  Rg0, tid);
  stage_half(VB, ldb, n0, 0,  Rg1, tid);
  stage_half(VA, ldb, n0, 64, Rg2, tid);
  VMC4;
  GBAR;
  LD_Bp(Rg0);
  SB0;

  bf16 *pBc = Rg0, *pBn = Rg1, *pBn2 = Rg2;
  bf16 *pAc = Ab0, *pAa = Ab1;
  for (int t = 0; t < NT; ++t) {
    // step 2t  (gate A, tile t): stage A(gate B, tile t), B(gate B, tile t+1)
    STEP2(accA, kgB + t * 64, VB, ((t + 1) & (NT - 1)) * 64);
    // step 2t+1 (gate B, tile t): stage A(gate A, tile t+1), B(gate A, tile t+2)
    STEP2(accB, kgA + ((t + 1) & (NT - 1)) * 64, VA, ((t + 2) & (NT - 1)) * 64);
  }
}

// ---------------- convert & concat x,h -> bf16 combined [8192][4096] ----------------

__global__ void k_convert_combined(const float* __restrict__ x,
                                   const float* __restrict__ h,
                                   bf16* __restrict__ out) {
  size_t i4 = (size_t)blockIdx.x * blockDim.x + threadIdx.x;
  size_t base = i4 * 4;
  int col = (int)(base & (KDIM - 1));
  size_t row = base >> 12;
  const float* src = (col < IN_DIM) ? (x + row * IN_DIM + col)
                                    : (h + row * (size_t)HID + (col - IN_DIM));
  float4 v = *(const float4*)src;
  union { bf16 b[4]; uint2 u; } p;
  p.b[0] = (bf16)v.x; p.b[1] = (bf16)v.y; p.b[2] = (bf16)v.z; p.b[3] = (bf16)v.w;
  *(uint2*)(out + base) = p.u;
}

// ---------------- vectorized tiled transpose + convert, 4 gates per launch ----------------
// 64x64 tile, 256 threads: float4 loads, bf16x8 (uint4) stores (32 B/thread).

__global__ void k_tconv4v(const float* __restrict__ s0, const float* __restrict__ s1,
                          const float* __restrict__ s2, const float* __restrict__ s3,
                          bf16* __restrict__ out, int nrow, int ncol,
                          long ostride, long gstride) {
  __shared__ float t[64][65];
  const float* in = blockIdx.z == 0 ? s0 : blockIdx.z == 1 ? s1
                  : blockIdx.z == 2 ? s2 : s3;
  bf16* o = out + (size_t)blockIdx.z * gstride;
  const int c0 = blockIdx.x * 64, r0 = blockIdx.y * 64;
  const int tid = threadIdx.x;

  {
    const int rb = tid >> 4;         // 0..15
    const int cq = (tid & 15) * 4;   // 0..60
    #pragma unroll
    for (int i = 0; i < 4; ++i) {
      const int rr = rb + i * 16;
      float4 v = *(const float4*)(in + (size_t)(r0 + rr) * ncol + c0 + cq);
      t[rr][cq] = v.x; t[rr][cq + 1] = v.y; t[rr][cq + 2] = v.z; t[rr][cq + 3] = v.w;
    }
  }
  __syncthreads();
  {
    const int orow = tid >> 2;        // 0..63  (output row = input col)
    const int cb = (tid & 3) * 16;    // 0..48  (output col base = input row)
    union { bf16 hh[8]; uint4 u; } p0, p1;
    #pragma unroll
    for (int k = 0; k < 8; ++k) p0.hh[k] = (bf16)t[cb + k][orow];
    #pragma unroll
    for (int k = 0; k < 8; ++k) p1.hh[k] = (bf16)t[cb + 8 + k][orow];
    bf16* ob = o + (size_t)(c0 + orow) * ostride + r0 + cb;
    *(uint4*)ob = p0.u;
    *(uint4*)(ob + 8) = p1.u;
  }
}

// ---------------- GEMM1: combined @ [Ui|Uf|Uc|Uo] -> R bf16 [8192][2048] ----------------

__launch_bounds__(512, 2)
__global__ void k_gemm1(const bf16* __restrict__ A,   // [8192][4096]
                        const bf16* __restrict__ Bt,  // [2048][4096]
                        bf16* __restrict__ R) {       // [8192][2048]
  __shared__ __align__(16) bf16 lds[81920];   // 160 KB
  const int bx = blockIdx.x;                  // 256 blocks
  const int id = (bx & 7) * 32 + (bx >> 3);   // XCD-bijective swizzle
  const int m0 = (id >> 3) * 256, n0 = (id & 7) * 256;
  f32x4 acc[8][4];
  gemm_core<KDIM / 64>(A, KDIM, m0, Bt, KDIM, n0, lds, acc);

  const int tid = threadIdx.x;
  const int wid = tid >> 6, lane = tid & 63;
  const int wm = (wid >> 2) * 128, wn = (wid & 3) * 64;
  const int lr = lane & 15, lk = lane >> 4;
  #pragma unroll
  for (int i = 0; i < 8; ++i)
    #pragma unroll
    for (int j = 0; j < 4; ++j)
      #pragma unroll
      for (int v = 0; v < 4; ++v)
        R[(size_t)(m0 + wm + i * 16 + lk * 4 + v) * NG + (n0 + wn + j * 16 + lr)] =
            (bf16)acc[i][j][v];
}

// ---------------- pair kernel 1: gates i,c -> sv = sigmoid(i)*tanh(c) ----------------

__launch_bounds__(512, 2)
__global__ void k_pair_ic(const bf16* __restrict__ Rb,   // [8192][2048]
                          const bf16* __restrict__ Vt,   // [4][2048][512]
                          const float* __restrict__ bi, const float* __restrict__ bc,
                          bf16* __restrict__ sv) {       // [8192][2048]
  __shared__ __align__(16) bf16 lds[57344];   // 112 KB
  const int bx = blockIdx.x;                  // 512 blocks
  const int id = (bx & 7) * 64 + (bx >> 3);   // XCD-bijective swizzle
  const int m0 = (id >> 4) * 256, n0 = (id & 15) * 128;

  f32x4 accI[4][4], accC[4][4];
  gemm_coreP2<RANK / 64>(Rb, NG, m0, 0 * RANK, 2 * RANK,
                         Vt + (size_t)0 * HID * RANK, Vt + (size_t)2 * HID * RANK,
                         RANK, n0, lds, accI, accC);

  const int tid = threadIdx.x;
  const int wid = tid >> 6, lane = tid & 63;
  const int wm = (wid >> 1) * 64, wn = (wid & 1) * 64;
  const int lr = lane & 15, lk = lane >> 4;
  #pragma unroll
  for (int j = 0; j < 4; ++j) {
    const int col = n0 + wn + j * 16 + lr;
    const float bji = bi[col], bjc = bc[col];
    #pragma unroll
    for (int q = 0; q < 4; ++q)
      #pragma unroll
      for (int v = 0; v < 4; ++v) {
        const int row = m0 + wm + q * 16 + lk * 4 + v;
        const float s = sigmoidf_(accI[q][j][v] + bji) * tanhf_(accC[q][j][v] + bjc);
        sv[(size_t)row * HID + col] = (bf16)s;
      }
  }
}

// ---------------- pair kernel 2: gates f,o + final LSTM combine ----------------

__launch_bounds__(512, 2)
__global__ void k_pair_fo(const bf16* __restrict__ Rb,   // [8192][2048]
                          const bf16* __restrict__ Vt,   // [4][2048][512]
                          const float* __restrict__ bf_, const float* __restrict__ bo,
                          const bf16* __restrict__ sv,   // [8192][2048]
                          const float* __restrict__ cin, // [8192][2048]
                          float* __restrict__ hout, float* __restrict__ cout) {
  __shared__ __align__(16) bf16 lds[57344];   // 112 KB
  const int bx = blockIdx.x;                  // 512 blocks
  const int id = (bx & 7) * 64 + (bx >> 3);   // XCD-bijective swizzle
  const int m0 = (id >> 4) * 256, n0 = (id & 15) * 128;

  f32x4 accF[4][4], accO[4][4];
  gemm_coreP2<RANK / 64>(Rb, NG, m0, 1 * RANK, 3 * RANK,
                         Vt + (size_t)1 * HID * RANK, Vt + (size_t)3 * HID * RANK,
                         RANK, n0, lds, accF, accO);

  const int tid = threadIdx.x;
  const int wid = tid >> 6, lane = tid & 63;
  const int wm = (wid >> 1) * 64, wn = (wid & 1) * 64;
  const int lr = lane & 15, lk = lane >> 4;
  #pragma unroll
  for (int j = 0; j < 4; ++j) {
    const int col = n0 + wn + j * 16 + lr;
    const float bjf = bf_[col], bjo = bo[col];
    #pragma unroll
    for (int q = 0; q < 4; ++q)
      #pragma unroll
      for (int v = 0; v < 4; ++v) {
        const int row = m0 + wm + q * 16 + lk * 4 + v;
        const size_t e = (size_t)row * HID + col;
        const float f = sigmoidf_(accF[q][j][v] + bjf);
        const float cn = f * cin[e] + (float)sv[e];
        cout[e] = cn;
        hout[e] = sigmoidf_(accO[q][j][v] + bjo) * tanhf_(cn);
      }
  }
}

// ---------------- launch ----------------

extern "C" void kernel_launch(void* const* d_in, const int* in_sizes, int n_in,
                              void* d_out, int out_size, void* d_ws, size_t ws_size,
                              hipStream_t stream) {
  const float* x = (const float*)d_in[0];
  const float* h = (const float*)d_in[1];
  const float* c = (const float*)d_in[2];
  const float* U[4] = {(const float*)d_in[3], (const float*)d_in[6],
                       (const float*)d_in[9], (const float*)d_in[12]};
  const float* V[4] = {(const float*)d_in[4], (const float*)d_in[7],
                       (const float*)d_in[10], (const float*)d_in[13]};
  const float* b[4] = {(const float*)d_in[5], (const float*)d_in[8],
                       (const float*)d_in[11], (const float*)d_in[14]};

  // Workspace (125,829,120 B):
  //   combined @ 0          : 67,108,864   (sv [33.5 MB] aliases it after gemm1)
  //   Ut       @ 67,108,864 : 16,777,216
  //   Vt       @ 83,886,080 :  8,388,608
  //   Rbuf     @ 92,274,688 : 33,554,432
  char* ws = (char*)d_ws;
  bf16* combined = (bf16*)ws;
  bf16* Ut       = (bf16*)(ws + 67108864);
  bf16* Vt       = (bf16*)(ws + 67108864 + 16777216);
  bf16* Rbuf     = (bf16*)(ws + 67108864 + 16777216 + 8388608);
  bf16* sv       = (bf16*)ws;   // aliases combined (dead after gemm1)

  float* hout = (float*)d_out;
  float* cout = hout + (size_t)BATCH * HID;

  k_convert_combined<<<(BATCH * (size_t)KDIM / 4) / 256, 256, 0, stream>>>(x, h, combined);

  k_tconv4v<<<dim3(RANK / 64, KDIM / 64, 4), 256, 0, stream>>>(
      U[0], U[1], U[2], U[3], Ut, KDIM, RANK, KDIM, (long)RANK * KDIM);
  k_tconv4v<<<dim3(HID / 64, RANK / 64, 4), 256, 0, stream>>>(
      V[0], V[1], V[2], V[3], Vt, RANK, HID, RANK, (long)HID * RANK);

  k_gemm1<<<256, 512, 0, stream>>>(combined, Ut, Rbuf);

  k_pair_ic<<<512, 512, 0, stream>>>(Rbuf, Vt, b[0], b[2], sv);
  k_pair_fo<<<512, 512, 0, stream>>>(Rbuf, Vt, b[1], b[3], sv, c, hout, cout);
}